// Round 8
// baseline (4590.027 us; speedup 1.0000x reference)
//
#include <hip/hip_runtime.h>
#include <math.h>

#define BB 256
#define SS 512
#define II 128
#define HH 256

#define WHH_LDS 12      // Whh chunks/wave LDS-resident (0..11)
#define WHH_REG 4       // Whh chunks in gate regs      (12..15)
#define WHH_STR 16      // streamed                      (16..31)
#define WA_XREG 8       // attn resident x-chunks per slice
#define WA_HREG 12      // attn resident h-chunks per slice
#define WA_HSTR 4       // attn streamed h-chunks per slice

typedef unsigned short ushort_t;
typedef unsigned int uint32;

// d_ws bf16 blob element offsets (each a multiple of 8 -> 16B aligned)
#define OFF_WA   0          // 128*384 = 49152   (swizzled, 48 chunks)
#define OFF_BA   49152      // 128
#define OFF_WIH  49280      // 768*128 = 98304   (swizzled, 16 chunks)
#define OFF_BIH  147584     // 768
#define OFF_WHH  148352     // 768*256 = 196608  (swizzled, 32 chunks)
#define OFF_BHH  344960     // 768
#define OFF_WT   345728     // 256
#define OFF_BT   345984     // 1 (padded to 8)
#define OFF_WF   345992     // 256
#define OFF_BF   346248     // 1

__device__ __forceinline__ float b2f(ushort_t u) {
    union { uint32 i; float f; } v; v.i = ((uint32)u) << 16; return v.f;
}
__device__ __forceinline__ float lo2f(uint32 w) {
    union { uint32 i; float f; } v; v.i = w << 16; return v.f;
}
__device__ __forceinline__ float hi2f(uint32 w) {
    union { uint32 i; float f; } v; v.i = w & 0xFFFF0000u; return v.f;
}
__device__ __forceinline__ ushort_t f2b(float f) {
    union { float f; uint32 i; } v; v.f = f;
    uint32 r = (v.i + 0x7FFFu + ((v.i >> 16) & 1u)) >> 16;
    return (ushort_t)r;
}
__device__ __forceinline__ uint32 pack2(float a, float b) {
    return (uint32)f2b(a) | ((uint32)f2b(b) << 16);
}

#if __has_builtin(__builtin_amdgcn_fdot2_f32_bf16)
typedef __bf16 v2bf __attribute__((ext_vector_type(2)));
__device__ __forceinline__ float dot2u(uint32 w, uint32 v, float acc) {
    return __builtin_amdgcn_fdot2_f32_bf16(
        __builtin_bit_cast(v2bf, w), __builtin_bit_cast(v2bf, v), acc, false);
}
#else
__device__ __forceinline__ float dot2u(uint32 w, uint32 v, float acc) {
    acc = fmaf(lo2f(w), lo2f(v), acc);
    return fmaf(hi2f(w), hi2f(v), acc);
}
#endif
__device__ __forceinline__ float dot4(uint4 w, uint4 v, float acc) {
    acc = dot2u(w.x, v.x, acc); acc = dot2u(w.y, v.y, acc);
    acc = dot2u(w.z, v.z, acc); return dot2u(w.w, v.w, acc);
}

// HW workgroup barrier WITHOUT the vmcnt(0) drain __syncthreads carries.
// lgkmcnt(0) makes this wave's LDS writes visible; global loads stay in
// flight across the barrier (the entire point). Waves parked at s_barrier
// consume no issue slots (vs. spin-polling, which burned ~87% of VALU issue
// in round 7).
__device__ __forceinline__ void wg_barrier() {
    asm volatile("s_waitcnt lgkmcnt(0)\n\ts_barrier" ::: "memory");
}

// fast activations (v_exp_f32 / v_rcp_f32); tolerance headroom is large
__device__ __forceinline__ float frcp(float x) { return __builtin_amdgcn_rcpf(x); }
__device__ __forceinline__ float fsigm(float x) { return frcp(1.f + __expf(-x)); }
__device__ __forceinline__ float ftanh(float x) {
    x = fminf(15.f, fmaxf(-15.f, x));
    float e = __expf(2.f * x);
    return (e - 1.f) * frcp(e + 1.f);
}

__global__ void cvt_f32_bf16(const float* __restrict__ src, ushort_t* __restrict__ dst, int n) {
    int i = blockIdx.x * 256 + threadIdx.x;
    if (i < n) dst[i] = f2b(src[i]);
}

// Swizzled fp32 -> bf16: uint4 index = ((row/64)*chunks + c)*64 + (row%64)
__global__ void cvt_swz(const float* __restrict__ src, ushort_t* __restrict__ dst,
                        int rows, int chunks) {
    int t = blockIdx.x * 256 + threadIdx.x;
    if (t >= rows * chunks) return;
    int row = t / chunks, c = t % chunks;
    const float* s = src + (size_t)row * chunks * 8 + c * 8;
    uint4 v;
    v.x = pack2(s[0], s[1]); v.y = pack2(s[2], s[3]);
    v.z = pack2(s[4], s[5]); v.w = pack2(s[6], s[7]);
    ((uint4*)dst)[((size_t)(row >> 6) * chunks + c) * 64 + (row & 63)] = v;
}

// One block (1024 threads) per batch row. 4 raw s_barriers per step, no spins.
// Waves 0-11 "gate": row tid of [Wih;Whh]; Wih 16 reg, Whh 12 LDS/4 reg/16 stream
//   (stream issued at A-top, half consumed in A, half carried in-flight to C).
// Waves 12-15 "attn": Wa slices (8x+12h reg, 4h stream), softmax (w12),
//   x-prefetch (w14-15), x-partial precompute (C), h-update (D).
__global__ __launch_bounds__(1024, 4) void da_rnn_kernel(
    const float* __restrict__ x,          // fp32 [B,S,I]
    const ushort_t* __restrict__ wsb,     // bf16 blob in d_ws
    float* __restrict__ out)              // fp32 [B,1]
{
    const int b    = blockIdx.x;
    const int tid  = threadIdx.x;
    const int lane = tid & 63;
    const int wv   = tid >> 6;
    const bool is_gate = (tid < 3 * HH);

    __shared__ __align__(16) uint32 whh_lds[12 * WHH_LDS * 256]; // 144 KB
    __shared__ __align__(16) uint32 s_xh_p[192];   // packed bf16 [x_t(128); h(256)]
    __shared__ __align__(16) uint32 sxw_p[64];     // packed bf16 alpha*x_t
    __shared__ __align__(16) float  sred[256];
    __shared__ __align__(16) float  sgi[3 * HH];
    __shared__ __align__(16) float  sgh[3 * HH];
    __shared__ __align__(16) float  sx[2][II];     // x_t fp32 double buffer
    __shared__ float swave[4];                     // temporal partials (per step)
    __shared__ float swout[4];                     // epilogue partials

    if (tid < II) s_xh_p[64 + tid] = 0u;           // h_0 = 0 (packed)

    const float* xrow = x + (size_t)b * SS * II;
    const uint4* st4 = (const uint4*)s_xh_p;       // 48 chunks of [x;h]
    const uint4* shp = (const uint4*)s_xh_p + 16;  // 32 chunks of h
    const uint4* xwp = (const uint4*)sxw_p;        // 16 chunks of xw

    if (is_gate) {
        // ======================= GATE PATH (waves 0-11) =======================
        uint4 wregg[16 + WHH_REG];                 // Wih 16 + Whh 4
        const uint4* wih_g = (const uint4*)(wsb + OFF_WIH) + (size_t)wv * 16 * 64 + lane;
        const uint4* whh_base = (const uint4*)(wsb + OFF_WHH) + (size_t)wv * 32 * 64 + lane;
        #pragma unroll
        for (int c = 0; c < 16; ++c) wregg[c] = wih_g[c * 64];
        #pragma unroll
        for (int i = 0; i < WHH_REG; ++i) wregg[16 + i] = whh_base[(WHH_LDS + i) * 64];
        const float bias_i = b2f(wsb[OFF_BIH + tid]);
        const float bias_h = b2f(wsb[OFF_BHH + tid]);
        #pragma unroll
        for (int c = 0; c < WHH_LDS; ++c)
            ((uint4*)whh_lds)[(wv * WHH_LDS + c) * 64 + lane] = whh_base[c * 64];
        const uint4* whl = (const uint4*)whh_lds + (size_t)(wv * WHH_LDS) * 64 + lane;

        __syncthreads();                           // prologue barrier

        for (int t = 0; t < SS; ++t) {
            // ---- PHASE A: issue 16 streamed loads, consume resident + 8 ----
            uint4 sld[WHH_STR];
            #pragma unroll
            for (int i = 0; i < WHH_STR; ++i) sld[i] = whh_base[(16 + i) * 64];
            float g0 = bias_h, g1 = 0.f;
            #pragma unroll
            for (int c = 0; c < WHH_LDS; c += 2) {
                g0 = dot4(whl[c * 64], shp[c], g0);
                g1 = dot4(whl[(c + 1) * 64], shp[c + 1], g1);
            }
            #pragma unroll
            for (int i = 0; i < WHH_REG; i += 2) {
                g0 = dot4(wregg[16 + i], shp[WHH_LDS + i], g0);
                g1 = dot4(wregg[17 + i], shp[WHH_LDS + i + 1], g1);
            }
            #pragma unroll
            for (int i = 0; i < 8; i += 2) {
                g0 = dot4(sld[i], shp[16 + i], g0);
                g1 = dot4(sld[i + 1], shp[17 + i], g1);
            }
            wg_barrier();                          // BAR1 (sred/sgh-partial era)
            // ---- PHASE B: idle (L2 still serving sld[8..16)) ----
            wg_barrier();                          // BAR2
            // ---- PHASE C: finish streamed gh + gi ----
            #pragma unroll
            for (int i = 8; i < 16; i += 2) {
                g0 = dot4(sld[i], shp[16 + i], g0);
                g1 = dot4(sld[i + 1], shp[17 + i], g1);
            }
            sgh[tid] = g0 + g1;
            float gi0 = bias_i, gi1 = 0.f;
            #pragma unroll
            for (int c = 0; c < 16; c += 2) {
                gi0 = dot4(wregg[c], xwp[c], gi0);     // uniform LDS broadcast
                gi1 = dot4(wregg[c + 1], xwp[c + 1], gi1);
            }
            sgi[tid] = gi0 + gi1;
            wg_barrier();                          // BAR3 (gates ready)
            // ---- PHASE D: idle ----
            wg_barrier();                          // BAR4 (h ready)
        }
    } else {
        // ======================= ATTN PATH (waves 12-15) =======================
        const int a   = tid - 3 * HH;              // 0..255
        const int row = a & 127;
        const int s   = a >> 7;                    // slice 0/1
        const int aw  = wv - 12;
        uint4 wrega[WA_XREG + WA_HREG];            // 8 x-chunks + 12 h-chunks
        const uint4* wa_g = (const uint4*)(wsb + OFF_WA);
        const size_t rbase = (size_t)(row >> 6) * 48 * 64 + (row & 63);
        #pragma unroll
        for (int i = 0; i < WA_XREG; ++i)
            wrega[i] = wa_g[rbase + (size_t)(8 * s + i) * 64];
        #pragma unroll
        for (int i = 0; i < WA_HREG; ++i)
            wrega[WA_XREG + i] = wa_g[rbase + (size_t)(16 + 16 * s + i) * 64];
        const uint4* wa_st = wa_g + rbase + (size_t)(16 + 16 * s + WA_HREG) * 64;
        const float ba_a = b2f(wsb[OFF_BA + lane]);
        const float ba_b = b2f(wsb[OFF_BA + 64 + lane]);
        const float wt_j = b2f(wsb[OFF_WT + a]);
        const float wf_j = b2f(wsb[OFF_WF + a]);
        const float bt_r = b2f(wsb[OFF_BT]);
        float h_reg = 0.f, c_reg = 0.f, m_run = -2.0f, l_run = 0.f;

        // x_0 load + pack (threads a<128)
        if (a < II) {
            float v = xrow[a];
            sx[0][a] = v;
            float vn = __shfl_down(v, 1);
            if (!(a & 1)) s_xh_p[a >> 1] = pack2(v, vn);
        }
        __syncthreads();                           // prologue barrier

        // initial x-partial for t=0
        float xpart;
        {
            float xp0 = 0.f, xp1 = 0.f;
            #pragma unroll
            for (int i = 0; i < WA_XREG; i += 2) {
                xp0 = dot4(wrega[i], st4[8 * s + i], xp0);
                xp1 = dot4(wrega[i + 1], st4[8 * s + i + 1], xp1);
            }
            xpart = xp0 + xp1;
        }

        for (int t = 0; t < SS; ++t) {
            const int p = t & 1;
            // ---- PHASE A: temporal update (t-1) + h-part dots ----
            uint4 ald[WA_HSTR];
            #pragma unroll
            for (int i = 0; i < WA_HSTR; ++i) ald[i] = wa_st[i * 64];
            if (t) {
                float dt = swave[0] + swave[1] + swave[2] + swave[3] + bt_r;
                float st = ftanh(dt);
                float mn = fmaxf(m_run, st);
                float aa = __expf(m_run - mn), ww = __expf(st - mn);
                l_run = l_run * aa + ww;
                m_run = mn;
                c_reg = c_reg * aa + ww * h_reg;
            }
            float a0 = xpart, a1 = 0.f;
            #pragma unroll
            for (int i = 0; i < WA_HREG; i += 2) {
                a0 = dot4(wrega[WA_XREG + i], st4[16 + 16 * s + i], a0);
                a1 = dot4(wrega[WA_XREG + i + 1], st4[16 + 16 * s + i + 1], a1);
            }
            #pragma unroll
            for (int i = 0; i < WA_HSTR; i += 2) {
                a0 = dot4(ald[i], st4[16 + 16 * s + WA_HREG + i], a0);
                a1 = dot4(ald[i + 1], st4[16 + 16 * s + WA_HREG + i + 1], a1);
            }
            sred[a] = a0 + a1;
            wg_barrier();                          // BAR1 (sred ready)

            // ---- PHASE B: softmax (w12) + x prefetch (w14-15) ----
            if (wv == 12) {
                float s_a = sred[lane] + sred[128 + lane] + ba_a;
                float s_b = sred[64 + lane] + sred[192 + lane] + ba_b;
                s_a = ftanh(s_a); s_b = ftanh(s_b);
                float m = fmaxf(s_a, s_b);
                for (int off = 32; off; off >>= 1) m = fmaxf(m, __shfl_xor(m, off));
                float e_a = __expf(s_a - m), e_b = __expf(s_b - m);
                float sum = e_a + e_b;
                for (int off = 32; off; off >>= 1) sum += __shfl_xor(sum, off);
                float inv = frcp(sum);
                float xa = e_a * inv * sx[p][lane];
                float xb = e_b * inv * sx[p][64 + lane];
                float xa1 = __shfl_down(xa, 1), xb1 = __shfl_down(xb, 1);
                if (!(lane & 1)) {
                    sxw_p[lane >> 1]        = pack2(xa, xa1);
                    sxw_p[32 + (lane >> 1)] = pack2(xb, xb1);
                }
            } else if (wv >= 14 && t + 1 < SS) {
                const int idx = a - 128;           // waves 14-15: 128 threads
                float v = xrow[(t + 1) * II + idx];
                sx[p ^ 1][idx] = v;
                float vn = __shfl_down(v, 1);
                if (!(idx & 1)) s_xh_p[idx >> 1] = pack2(v, vn);
            }
            wg_barrier();                          // BAR2 (xw + x_{t+1} ready)

            // ---- PHASE C: x-partials for t+1 ----
            {
                float xp0 = 0.f, xp1 = 0.f;
                #pragma unroll
                for (int i = 0; i < WA_XREG; i += 2) {
                    xp0 = dot4(wrega[i], st4[8 * s + i], xp0);
                    xp1 = dot4(wrega[i + 1], st4[8 * s + i + 1], xp1);
                }
                xpart = xp0 + xp1;
            }
            wg_barrier();                          // BAR3 (sgi/sgh ready)

            // ---- PHASE D: h update (one hidden unit per attn thread) ----
            {
                const float r = fsigm(sgi[a] + sgh[a]);
                const float z = fsigm(sgi[a + HH] + sgh[a + HH]);
                const float n = ftanh(sgi[a + 2 * HH] + r * sgh[a + 2 * HH]);
                h_reg = (1.f - z) * n + z * h_reg;
                float hn2 = __shfl_down(h_reg, 1);
                if (!(a & 1)) s_xh_p[64 + (a >> 1)] = pack2(h_reg, hn2);
                float pd = wt_j * h_reg;
                for (int off = 32; off; off >>= 1) pd += __shfl_down(pd, off);
                if (lane == 0) swave[aw] = pd;
            }
            wg_barrier();                          // BAR4 (h + swave ready)
        }

        // epilogue: final temporal update (t=511) + context + Wf dot
        {
            float dt = swave[0] + swave[1] + swave[2] + swave[3] + bt_r;
            float st = ftanh(dt);
            float mn = fmaxf(m_run, st);
            float aa = __expf(m_run - mn), ww = __expf(st - mn);
            l_run = l_run * aa + ww;
            c_reg = c_reg * aa + ww * h_reg;
            float ctx = c_reg * frcp(l_run);
            float pd = wf_j * ctx;
            for (int off = 32; off; off >>= 1) pd += __shfl_down(pd, off);
            if (lane == 0) swout[aw] = pd;
        }
    }

    // ---- final combine ----
    __syncthreads();
    if (tid == 0) {
        float logit = swout[0] + swout[1] + swout[2] + swout[3] + b2f(wsb[OFF_BF]);
        out[b] = fsigm(logit);
    }
}

extern "C" void kernel_launch(void* const* d_in, const int* in_sizes, int n_in,
                              void* d_out, int out_size, void* d_ws, size_t ws_size,
                              hipStream_t stream) {
    ushort_t* wsb = (ushort_t*)d_ws;

    cvt_swz<<<dim3((128 * 48 + 255) / 256), dim3(256), 0, stream>>>(
        (const float*)d_in[1], wsb + OFF_WA, 128, 48);           // W_a  [128,384]
    cvt_swz<<<dim3((768 * 16 + 255) / 256), dim3(256), 0, stream>>>(
        (const float*)d_in[3], wsb + OFF_WIH, 768, 16);          // W_ih [768,128]
    cvt_swz<<<dim3((768 * 32 + 255) / 256), dim3(256), 0, stream>>>(
        (const float*)d_in[5], wsb + OFF_WHH, 768, 32);          // W_hh [768,256]

    struct { int src_idx; int off; int n; } cv[7] = {
        {2, OFF_BA,  II}, {4, OFF_BIH, 3 * HH}, {6, OFF_BHH, 3 * HH},
        {7, OFF_WT,  HH}, {8, OFF_BT, 1}, {9, OFF_WF, HH}, {10, OFF_BF, 1},
    };
    for (int i = 0; i < 7; ++i) {
        int blocks = (cv[i].n + 255) / 256;
        cvt_f32_bf16<<<dim3(blocks), dim3(256), 0, stream>>>(
            (const float*)d_in[cv[i].src_idx], wsb + cv[i].off, cv[i].n);
    }

    da_rnn_kernel<<<dim3(BB), dim3(1024), 0, stream>>>(
        (const float*)d_in[0], wsb, (float*)d_out);
}